// Round 1
// baseline (709.861 us; speedup 1.0000x reference)
//
#include <hip/hip_runtime.h>
#include <hip/hip_bf16.h>
#include <stdint.h>

typedef __attribute__((ext_vector_type(8))) short short8;
typedef __attribute__((ext_vector_type(4))) float floatx4;
typedef unsigned short u16;

#define IN_DIM  1024
#define OUT_DIM 1024
#define NG      11            // GRID_SIZE + K
#define GK      12            // NG + 1 (silu slot)
#define KDIM    (IN_DIM * GK) // 12288
#define TOKENS  8192

__device__ __forceinline__ u16 f2bf(float f) {
  uint32_t u = __float_as_uint(f);
  uint32_t r = (u + 0x7fffu + ((u >> 16) & 1u)) >> 16;  // RNE
  return (u16)r;
}

__device__ __forceinline__ void store12(u16* dst, const u16* h) {
  uint64_t w0 = (uint64_t)h[0] | ((uint64_t)h[1] << 16) | ((uint64_t)h[2] << 32) | ((uint64_t)h[3] << 48);
  uint64_t w1 = (uint64_t)h[4] | ((uint64_t)h[5] << 16) | ((uint64_t)h[6] << 32) | ((uint64_t)h[7] << 48);
  uint64_t w2 = (uint64_t)h[8] | ((uint64_t)h[9] << 16) | ((uint64_t)h[10] << 32) | ((uint64_t)h[11] << 48);
  uint64_t* p = reinterpret_cast<uint64_t*>(dst);  // 24B-group, 8B aligned
  p[0] = w0; p[1] = w1; p[2] = w2;
}

// ---------------- pack Wt: bf16 [OUT_DIM][KDIM], row o, group i: coeff[o][i][0..10]*ss, scale_base[o][i]
__global__ __launch_bounds__(256) void pack_wt_kernel(
    const float* __restrict__ coeff, const float* __restrict__ sb,
    const float* __restrict__ ss_p, u16* __restrict__ Wt)
{
  int idx = blockIdx.x * 256 + threadIdx.x;   // 1024*1024 threads
  int o = idx >> 10, i = idx & 1023;
  float ss = ss_p[0];
  const float* cp = coeff + (size_t)o * (IN_DIM * NG) + (size_t)i * NG;
  u16 h[GK];
#pragma unroll
  for (int g = 0; g < NG; ++g) h[g] = f2bf(cp[g] * ss);
  h[NG] = f2bf(sb[(size_t)o * IN_DIM + i]);
  store12(Wt + (size_t)o * KDIM + (size_t)i * GK, h);
}

// ---------------- expand: bf16 A[rows][KDIM]; group i: bases(x[b][i])[0..10], silu(x[b][i])
__global__ __launch_bounds__(256) void expand_kernel(
    const float* __restrict__ X, const float* __restrict__ grid,
    u16* __restrict__ A, int m0)
{
  int idx = blockIdx.x * 256 + threadIdx.x;   // rows*1024 threads
  int b = idx >> 10, i = idx & 1023;
  float x = X[(size_t)(m0 + b) * IN_DIM + i];
  const float* gp = grid + i * 15;
  float gr[15];
#pragma unroll
  for (int j = 0; j < 15; ++j) gr[j] = gp[j];
  float bs[14];
#pragma unroll
  for (int j = 0; j < 14; ++j) bs[j] = (x >= gr[j] && x < gr[j + 1]) ? 1.0f : 0.0f;
#pragma unroll
  for (int kk = 1; kk <= 3; ++kk) {
#pragma unroll
    for (int j = 0; j < 14 - kk; ++j) {
      // in-place forward: bs[j] uses old bs[j], old bs[j+1]
      bs[j] = (x - gr[j]) / (gr[j + kk] - gr[j]) * bs[j]
            + (gr[j + kk + 1] - x) / (gr[j + kk + 1] - gr[j + 1]) * bs[j + 1];
    }
  }
  float silu = x / (1.0f + __expf(-x));
  u16 h[GK];
#pragma unroll
  for (int j = 0; j < NG; ++j) h[j] = f2bf(bs[j]);
  h[NG] = f2bf(silu);
  store12(A + (size_t)b * KDIM + (size_t)i * GK, h);
}

// ---------------- GEMM: out[m0+.., :] = A[rows][KDIM] * Wt[1024][KDIM]^T   (m97 structure)
__device__ __forceinline__ void async16(const u16* g, u16* l) {
  __builtin_amdgcn_global_load_lds(
      (const __attribute__((address_space(1))) uint32_t*)g,
      (__attribute__((address_space(3))) uint32_t*)l,
      16 /*bytes*/, 0 /*offset*/, 0 /*aux*/);
}

__global__ __launch_bounds__(256) void gemm_kernel(
    const u16* __restrict__ A, const u16* __restrict__ Wt,
    float* __restrict__ out, int m0)
{
  __shared__ __align__(16) u16 As[128 * 32];
  __shared__ __align__(16) u16 Bs[128 * 32];

  const int tid  = threadIdx.x;
  const int lane = tid & 63;
  const int wave = tid >> 6;
  const int bn = blockIdx.x & 7;     // XCD swizzle: same bn -> same XCD -> W-strip L2-resident
  const int bm = blockIdx.x >> 3;
  const int wm = (wave >> 1) * 64;   // wave tile origin in M
  const int wn = (wave & 1) * 64;    // wave tile origin in N

  floatx4 acc[4][4];
#pragma unroll
  for (int a = 0; a < 4; ++a)
#pragma unroll
    for (int b = 0; b < 4; ++b) acc[a][b] = (floatx4){0.f, 0.f, 0.f, 0.f};

  // staging: each global_load_lds covers 16 rows (64 lanes x 16B, 64B per row of 32 bf16)
  const int srow = wave * 32 + (lane >> 2);
  const int scol = (lane & 3) * 8;
  const u16* Ag = A  + (size_t)(bm * 128 + srow) * KDIM + scol;
  const u16* Bg = Wt + (size_t)(bn * 128 + srow) * KDIM + scol;
  u16* Al0 = As + (wave * 32) * 32;        // wave-uniform LDS bases
  u16* Al1 = As + (wave * 32 + 16) * 32;
  u16* Bl0 = Bs + (wave * 32) * 32;
  u16* Bl1 = Bs + (wave * 32 + 16) * 32;

  const int quad = lane >> 4;
  const int l16  = lane & 15;

  for (int k0 = 0; k0 < KDIM; k0 += 32) {
    async16(Ag + k0,                 Al0);
    async16(Ag + k0 + (size_t)16 * KDIM, Al1);
    async16(Bg + k0,                 Bl0);
    async16(Bg + k0 + (size_t)16 * KDIM, Bl1);
    __syncthreads();   // drains vmcnt -> LDS tiles complete

    short8 af[4], bf[4];
#pragma unroll
    for (int s = 0; s < 4; ++s)
      af[s] = *(const short8*)&As[(wm + s * 16 + l16) * 32 + quad * 8];
#pragma unroll
    for (int s = 0; s < 4; ++s)
      bf[s] = *(const short8*)&Bs[(wn + s * 16 + l16) * 32 + quad * 8];

#pragma unroll
    for (int sm = 0; sm < 4; ++sm)
#pragma unroll
      for (int sn = 0; sn < 4; ++sn)
        acc[sm][sn] = __builtin_amdgcn_mfma_f32_16x16x32_bf16(af[sm], bf[sn], acc[sm][sn], 0, 0, 0);

    __syncthreads();   // compute done before next stage overwrites
  }

  // epilogue: C/D map col=lane&15, row=(lane>>4)*4+reg
#pragma unroll
  for (int sm = 0; sm < 4; ++sm)
#pragma unroll
    for (int sn = 0; sn < 4; ++sn) {
      int row0 = m0 + bm * 128 + wm + sm * 16 + quad * 4;
      int col  = bn * 128 + wn + sn * 16 + l16;
#pragma unroll
      for (int r = 0; r < 4; ++r)
        out[(size_t)(row0 + r) * OUT_DIM + col] = acc[sm][sn][r];
    }
}

extern "C" void kernel_launch(void* const* d_in, const int* in_sizes, int n_in,
                              void* d_out, int out_size, void* d_ws, size_t ws_size,
                              hipStream_t stream) {
  const float* x     = (const float*)d_in[0];
  const float* grid  = (const float*)d_in[1];
  const float* coeff = (const float*)d_in[2];
  const float* sb    = (const float*)d_in[3];
  const float* ss    = (const float*)d_in[4];
  float* out = (float*)d_out;

  u16* Wt = (u16*)d_ws;
  const size_t wt_bytes = (size_t)OUT_DIM * KDIM * 2;   // 25,165,824 (256-aligned)
  u16* Abuf = (u16*)((char*)d_ws + wt_bytes);

  // Row-chunking sized from ws_size (constant per session -> identical work every call)
  size_t avail   = ws_size > wt_bytes ? ws_size - wt_bytes : 0;
  size_t maxrows = avail / ((size_t)KDIM * 2);
  int chunk = (int)(maxrows & ~(size_t)127);
  if (chunk > TOKENS) chunk = TOKENS;
  if (chunk < 128)    chunk = 128;   // minimum viable; requires ws_size >= ~28.3 MB

  pack_wt_kernel<<<(OUT_DIM * IN_DIM) / 256, 256, 0, stream>>>(coeff, sb, ss, Wt);

  for (int m0 = 0; m0 < TOKENS; m0 += chunk) {
    int rows = TOKENS - m0 < chunk ? TOKENS - m0 : chunk;   // multiple of 128
    expand_kernel<<<(rows * IN_DIM) / 256, 256, 0, stream>>>(x, grid, Abuf, m0);
    gemm_kernel<<<(rows / 128) * 8, 256, 0, stream>>>(Abuf, Wt, out, m0);
  }
}

// Round 2
// 630.159 us; speedup vs baseline: 1.1265x; 1.1265x over previous
//
#include <hip/hip_runtime.h>
#include <hip/hip_bf16.h>
#include <stdint.h>

typedef __attribute__((ext_vector_type(8))) short short8;
typedef __attribute__((ext_vector_type(4))) float floatx4;
typedef unsigned short u16;

#define IN_DIM  1024
#define OUT_DIM 1024
#define NG      11            // GRID_SIZE + K
#define GK      12            // NG + 1 (silu slot)
#define KDIM    (IN_DIM * GK) // 12288
#define TOKENS  8192
#define BK      64            // K-tile (2 MFMA k-steps); halves barrier count vs 32

__device__ __forceinline__ u16 f2bf(float f) {
  uint32_t u = __float_as_uint(f);
  uint32_t r = (u + 0x7fffu + ((u >> 16) & 1u)) >> 16;  // RNE
  return (u16)r;
}

// ---------------- pack Wt: bf16 [OUT_DIM][KDIM]; group i: coeff[o][i][0..10]*ss, scale_base[o][i]
// LDS-staged so global writes are contiguous 16B uint4 stores (R1: stride-24B stores cost ~100s of us)
__global__ __launch_bounds__(256) void pack_wt_kernel(
    const float* __restrict__ coeff, const float* __restrict__ sb,
    const float* __restrict__ ss_p, u16* __restrict__ Wt)
{
  __shared__ __align__(16) u16 st[256 * GK];   // 6144 B
  int tid = threadIdx.x;
  int idx = blockIdx.x * 256 + tid;            // 1024*1024 threads, i fastest
  int o = idx >> 10, i = idx & 1023;
  float ss = ss_p[0];
  const float* cp = coeff + (size_t)o * (IN_DIM * NG) + (size_t)i * NG;
  u16* s = st + tid * GK;
#pragma unroll
  for (int g = 0; g < NG; ++g) s[g] = f2bf(cp[g] * ss);
  s[NG] = f2bf(sb[(size_t)o * IN_DIM + i]);
  __syncthreads();
  const uint4* src = (const uint4*)st;         // 384 uint4
  uint4* dst = (uint4*)(Wt + (size_t)blockIdx.x * (256 * GK));
  dst[tid] = src[tid];
  if (tid < 128) dst[256 + tid] = src[256 + tid];
}

// ---------------- expand: bf16 A[rows][KDIM]; group i: bases(x)[0..10], silu(x). LDS-staged writes.
__global__ __launch_bounds__(256) void expand_kernel(
    const float* __restrict__ X, const float* __restrict__ grid,
    u16* __restrict__ A, int m0)
{
  __shared__ __align__(16) u16 st[256 * GK];
  int tid = threadIdx.x;
  int idx = blockIdx.x * 256 + tid;            // rows*1024 threads, i fastest (256 | 1024 -> no row split)
  int b = idx >> 10, i = idx & 1023;
  float x = X[(size_t)(m0 + b) * IN_DIM + i];
  const float* gp = grid + i * 15;
  float gr[15];
#pragma unroll
  for (int j = 0; j < 15; ++j) gr[j] = gp[j];
  float bs[14];
#pragma unroll
  for (int j = 0; j < 14; ++j) bs[j] = (x >= gr[j] && x < gr[j + 1]) ? 1.0f : 0.0f;
#pragma unroll
  for (int kk = 1; kk <= 3; ++kk) {
#pragma unroll
    for (int j = 0; j < 14 - kk; ++j) {
      bs[j] = (x - gr[j]) / (gr[j + kk] - gr[j]) * bs[j]
            + (gr[j + kk + 1] - x) / (gr[j + kk + 1] - gr[j + 1]) * bs[j + 1];
    }
  }
  float silu = x / (1.0f + __expf(-x));
  u16* s = st + tid * GK;
#pragma unroll
  for (int j = 0; j < NG; ++j) s[j] = f2bf(bs[j]);
  s[NG] = f2bf(silu);
  __syncthreads();
  const uint4* src = (const uint4*)st;
  uint4* dst = (uint4*)(A + (size_t)blockIdx.x * (256 * GK));
  dst[tid] = src[tid];
  if (tid < 128) dst[256 + tid] = src[256 + tid];
}

// ---------------- GEMM: out = A[rows][KDIM] * Wt[1024][KDIM]^T  (m97 structure, BK=64, XOR swizzle)
__device__ __forceinline__ void async16(const u16* g, u16* l) {
  __builtin_amdgcn_global_load_lds(
      (const __attribute__((address_space(1))) uint32_t*)g,
      (__attribute__((address_space(3))) uint32_t*)l,
      16, 0, 0);
}

__global__ __launch_bounds__(256) void gemm_kernel(
    const u16* __restrict__ A, const u16* __restrict__ Wt,
    float* __restrict__ out, int m0)
{
  // Row stride BK=64 u16 = 128 B = exactly 32 banks -> unswizzled reads would be 16-way conflicted.
  // XOR swizzle: 16B chunk gamma of row r lives at slot (gamma ^ (r&7)) -> 2-way (free, m136).
  __shared__ __align__(16) u16 As[128 * BK];   // 16 KB
  __shared__ __align__(16) u16 Bs[128 * BK];   // 16 KB

  const int tid  = threadIdx.x;
  const int lane = tid & 63;
  const int wave = tid >> 6;
  const int bn = blockIdx.x & 7;     // XCD swizzle: W-strip (3MB) stays in that XCD's L2
  const int bm = blockIdx.x >> 3;
  const int wm = (wave >> 1) * 64;
  const int wn = (wave & 1) * 64;

  floatx4 acc[4][4];
#pragma unroll
  for (int a = 0; a < 4; ++a)
#pragma unroll
    for (int b = 0; b < 4; ++b) acc[a][b] = (floatx4){0.f, 0.f, 0.f, 0.f};

  // Staging: each async16 op covers 8 rows x 128B. Lane l -> LDS slot (row=l>>3, chunk=l&7).
  // To realize the swizzle, lane l fetches global chunk gamma = (l&7) ^ (l>>3) of its row
  // (row base R0 is a multiple of 8, so (R0+r)&7 == r). Union per row is a full 128B -> still coalesced.
  const int srow  = lane >> 3;
  const int gamma = (lane & 7) ^ srow;
  const u16* Ag = A  + (size_t)(bm * 128 + wave * 32 + srow) * KDIM + gamma * 8;
  const u16* Bg = Wt + (size_t)(bn * 128 + wave * 32 + srow) * KDIM + gamma * 8;
  u16* Al = As + (wave * 32) * BK;   // wave-uniform LDS bases
  u16* Bl = Bs + (wave * 32) * BK;

  const int quad = lane >> 4;
  const int l16  = lane & 15;
  const int sw   = l16 & 7;          // read-side swizzle key: row&7 == l16&7 (wm, s*16 are mult of 8)

  for (int k0 = 0; k0 < KDIM; k0 += BK) {
#pragma unroll
    for (int op = 0; op < 4; ++op) {
      async16(Ag + k0 + (size_t)(op * 8) * KDIM, Al + op * 8 * BK);
      async16(Bg + k0 + (size_t)(op * 8) * KDIM, Bl + op * 8 * BK);
    }
    __syncthreads();   // drains vmcnt -> tiles complete

    short8 af[4][2], bf[4][2];
#pragma unroll
    for (int s = 0; s < 4; ++s)
#pragma unroll
      for (int t = 0; t < 2; ++t) {
        int c = (t * 4 + quad) ^ sw;
        af[s][t] = *(const short8*)&As[(wm + s * 16 + l16) * BK + c * 8];
        bf[s][t] = *(const short8*)&Bs[(wn + s * 16 + l16) * BK + c * 8];
      }

#pragma unroll
    for (int sm = 0; sm < 4; ++sm)
#pragma unroll
      for (int sn = 0; sn < 4; ++sn)
#pragma unroll
        for (int t = 0; t < 2; ++t)
          acc[sm][sn] = __builtin_amdgcn_mfma_f32_16x16x32_bf16(af[sm][t], bf[sn][t], acc[sm][sn], 0, 0, 0);

    __syncthreads();
  }

  // epilogue: C/D map col=lane&15, row=(lane>>4)*4+reg
#pragma unroll
  for (int sm = 0; sm < 4; ++sm)
#pragma unroll
    for (int sn = 0; sn < 4; ++sn) {
      int row0 = m0 + bm * 128 + wm + sm * 16 + quad * 4;
      int col  = bn * 128 + wn + sn * 16 + l16;
#pragma unroll
      for (int r = 0; r < 4; ++r)
        out[(size_t)(row0 + r) * OUT_DIM + col] = acc[sm][sn][r];
    }
}

extern "C" void kernel_launch(void* const* d_in, const int* in_sizes, int n_in,
                              void* d_out, int out_size, void* d_ws, size_t ws_size,
                              hipStream_t stream) {
  const float* x     = (const float*)d_in[0];
  const float* grid  = (const float*)d_in[1];
  const float* coeff = (const float*)d_in[2];
  const float* sb    = (const float*)d_in[3];
  const float* ss    = (const float*)d_in[4];
  float* out = (float*)d_out;

  u16* Wt = (u16*)d_ws;
  const size_t wt_bytes = (size_t)OUT_DIM * KDIM * 2;   // 25,165,824 (16B-aligned)
  u16* Abuf = (u16*)((char*)d_ws + wt_bytes);

  size_t avail   = ws_size > wt_bytes ? ws_size - wt_bytes : 0;
  size_t maxrows = avail / ((size_t)KDIM * 2);
  int chunk = (int)(maxrows & ~(size_t)127);
  if (chunk > TOKENS) chunk = TOKENS;
  if (chunk < 128)    chunk = 128;

  pack_wt_kernel<<<(OUT_DIM * IN_DIM) / 256, 256, 0, stream>>>(coeff, sb, ss, Wt);

  for (int m0 = 0; m0 < TOKENS; m0 += chunk) {
    int rows = TOKENS - m0 < chunk ? TOKENS - m0 : chunk;   // multiple of 128
    expand_kernel<<<(rows * IN_DIM) / 256, 256, 0, stream>>>(x, grid, Abuf, m0);
    gemm_kernel<<<(rows / 128) * 8, 256, 0, stream>>>(Abuf, Wt, out, m0);
  }
}

// Round 3
// 569.273 us; speedup vs baseline: 1.2470x; 1.1070x over previous
//
#include <hip/hip_runtime.h>
#include <hip/hip_bf16.h>
#include <stdint.h>

typedef __attribute__((ext_vector_type(8))) short short8;
typedef __attribute__((ext_vector_type(4))) float floatx4;
typedef unsigned short u16;

#define IN_DIM  1024
#define OUT_DIM 1024
#define NG      11            // spline bases per channel
#define GK      12            // + silu slot
#define KDIM    (IN_DIM * GK) // 12288
#define TOKENS  8192
#define BK      96            // 8 channels x 12 slots = 3 mfma k-steps
#define PB      104           // padded LDS row stride (u16). dword-stride 52 == 20 mod 32 -> 2-way banks (free)
#define CH_IT   8             // channels per K-iter
#define NIT     (IN_DIM / CH_IT)  // 128 iters

__device__ __forceinline__ u16 f2bf(float f) {
  uint32_t u = __float_as_uint(f);
  uint32_t r = (u + 0x7fffu + ((u >> 16) & 1u)) >> 16;  // RNE
  return (u16)r;
}

// ---------------- pack Wt: bf16 [OUT_DIM][KDIM]; group i: coeff[o][i][0..10]*ss, scale_base[o][i]
__global__ __launch_bounds__(256) void pack_wt_kernel(
    const float* __restrict__ coeff, const float* __restrict__ sb,
    const float* __restrict__ ss_p, u16* __restrict__ Wt)
{
  __shared__ __align__(16) u16 st[256 * GK];
  int tid = threadIdx.x;
  int idx = blockIdx.x * 256 + tid;
  int o = idx >> 10, i = idx & 1023;
  float ss = ss_p[0];
  const float* cp = coeff + (size_t)o * (IN_DIM * NG) + (size_t)i * NG;
  u16* s = st + tid * GK;
#pragma unroll
  for (int g = 0; g < NG; ++g) s[g] = f2bf(cp[g] * ss);
  s[NG] = f2bf(sb[(size_t)o * IN_DIM + i]);
  __syncthreads();
  const uint4* src = (const uint4*)st;
  uint4* dst = (uint4*)(Wt + (size_t)blockIdx.x * (256 * GK));
  dst[tid] = src[tid];
  if (tid < 128) dst[256 + tid] = src[256 + tid];
}

// Closed-form cubic B-spline expansion (uniform grid). Only bases j = c-3..c are nonzero;
// values are the 4 cardinal pieces at u. Scatters the 4 bf16 values (dword-granular, trash-
// redirected for clipped j) into the zeroed 12-slot group; silu lands in slot 11 last
// (also kills any j==11 garbage). Verified against Cox-de Boor edge cases c=0,1,11,12,13.
__device__ __forceinline__ void expand_store(u16* __restrict__ gp, u16* __restrict__ trash,
                                             float x, float g0, float inv_h)
{
  float t  = (x - g0) * inv_h;
  float fc = floorf(t);
  int   c  = (int)fc;
  float u  = t - fc;
  float u2 = u * u;
  float w1 = 1.0f - u;
  float b0 = (w1 * w1 * w1) * (1.0f / 6.0f);          // j = c-3
  float b1 = (0.5f * u - 1.0f) * u2 + (2.0f / 3.0f);  // j = c-2
  float b2 = ((-0.5f * u + 0.5f) * u + 0.5f) * u + (1.0f / 6.0f);  // j = c-1
  float b3 = (u2 * u) * (1.0f / 6.0f);                // j = c
  float sil = x / (1.0f + __expf(-x));

  uint32_t p0 = (uint32_t)f2bf(b0) | ((uint32_t)f2bf(b1) << 16);
  uint32_t p1 = (uint32_t)f2bf(b2) | ((uint32_t)f2bf(b3) << 16);

  int  k   = c - 3;            // first slot
  int  d0  = k >> 1;           // arithmetic shift: floor
  bool odd = (k & 1) != 0;
  uint32_t q0 = odd ? (p0 << 16) : p0;
  uint32_t q1 = odd ? ((p0 >> 16) | (p1 << 16)) : p1;
  uint32_t q2 = odd ? (p1 >> 16) : 0u;
  bool cv = (c >= 0) && (c <= 13);

  uint64_t* g64 = (uint64_t*)gp;        // group base is 8B-aligned (row*208 + chl*24)
  g64[0] = 0ull; g64[1] = 0ull; g64[2] = 0ull;

  uint32_t* g32 = (uint32_t*)gp;
  uint32_t* t32 = (uint32_t*)trash;
  int d = d0;
  uint32_t* w0p = (cv && d >= 0 && d <= 5) ? (g32 + d) : t32; *w0p = q0;
  d = d0 + 1;
  uint32_t* w1p = (cv && d >= 0 && d <= 5) ? (g32 + d) : t32; *w1p = q1;
  d = d0 + 2;
  uint32_t* w2p = (cv && d >= 0 && d <= 5) ? (g32 + d) : t32; *w2p = q2;

  gp[NG] = f2bf(sil);   // slot 11, written last (same-lane DS ops are ordered)
}

// ---------------- fused GEMM: out[8192,1024] = expand(x)[8192,12288] * Wt[1024,12288]^T
__global__ __launch_bounds__(256, 3) void gemm_fused_kernel(
    const float* __restrict__ X, const float* __restrict__ grid,
    const u16* __restrict__ Wt, float* __restrict__ out)
{
  __shared__ __align__(16) u16 As[128 * PB];   // 26624 B
  __shared__ __align__(16) u16 Bs[128 * PB];   // 26624 B
  __shared__ __align__(16) u16 trash[16];      // clipped-scatter sink

  const int tid  = threadIdx.x;
  const int lane = tid & 63;
  const int wave = tid >> 6;
  const int bn = blockIdx.x & 7;     // == XCD id: each XCD's 64 blocks share one 3MB Wt strip in its L2
  const int bm = blockIdx.x >> 3;
  const int wm = (wave >> 1) * 64;
  const int wn = (wave & 1) * 64;

  const float g0    = grid[0];
  const float inv_h = 1.0f / (grid[1] - grid[0]);   // grid is uniform (tile of one arange row)

  floatx4 acc[4][4];
#pragma unroll
  for (int a = 0; a < 4; ++a)
#pragma unroll
    for (int b = 0; b < 4; ++b) acc[a][b] = (floatx4){0.f, 0.f, 0.f, 0.f};

  // --- B staging setup: 6 ops/wave cover this wave's 32 rows x 192 B (12 chunks of 16B per row)
  const u16* bgp[6];
  u16*       blp[6];
#pragma unroll
  for (int o = 0; o < 6; ++o) {
    int q  = o * 64 + lane;
    int rl = q / 12;            // 0..31
    int cr = q - rl * 12;       // 0..11
    bgp[o] = Wt + (size_t)(bn * 128 + wave * 32 + rl) * KDIM + cr * 8;
    blp[o] = Bs + (wave * 32 + rl) * PB + cr * 8;
  }

  // --- A expansion assignment: thread -> (row, 4 channels)
  const int row = tid & 127;
  const int chb = (tid >> 7) * 4;   // 0 or 4
  const float* xp = X + (size_t)(bm * 128 + row) * IN_DIM + chb;
  u16* agp = As + row * PB + chb * GK;   // first group; groups are 24B apart

  const int quad = lane >> 4;
  const int l16  = lane & 15;

  for (int it = 0; it < NIT; ++it) {
    // B tile global loads (in flight during expansion VALU)
    uint4 bv[6];
#pragma unroll
    for (int o = 0; o < 6; ++o) { bv[o] = *(const uint4*)bgp[o]; bgp[o] += BK; }

    // A tile: expand 4 channels of this thread's row
    float4 xv = *(const float4*)(xp + it * CH_IT);
    expand_store(agp + 0 * GK, trash, xv.x, g0, inv_h);
    expand_store(agp + 1 * GK, trash, xv.y, g0, inv_h);
    expand_store(agp + 2 * GK, trash, xv.z, g0, inv_h);
    expand_store(agp + 3 * GK, trash, xv.w, g0, inv_h);

    // B tile LDS writes (compiler inserts vmcnt waits)
#pragma unroll
    for (int o = 0; o < 6; ++o) *(uint4*)blp[o] = bv[o];

    __syncthreads();

#pragma unroll
    for (int t = 0; t < 3; ++t) {
      short8 af[4], bf[4];
#pragma unroll
      for (int s = 0; s < 4; ++s)
        af[s] = *(const short8*)&As[(wm + s * 16 + l16) * PB + t * 32 + quad * 8];
#pragma unroll
      for (int s = 0; s < 4; ++s)
        bf[s] = *(const short8*)&Bs[(wn + s * 16 + l16) * PB + t * 32 + quad * 8];
#pragma unroll
      for (int sm = 0; sm < 4; ++sm)
#pragma unroll
        for (int sn = 0; sn < 4; ++sn)
          acc[sm][sn] = __builtin_amdgcn_mfma_f32_16x16x32_bf16(af[sm], bf[sn], acc[sm][sn], 0, 0, 0);
    }

    __syncthreads();
  }

  // epilogue: C/D map col=lane&15, row=(lane>>4)*4+reg
#pragma unroll
  for (int sm = 0; sm < 4; ++sm)
#pragma unroll
    for (int sn = 0; sn < 4; ++sn) {
      int row0 = bm * 128 + wm + sm * 16 + quad * 4;
      int col  = bn * 128 + wn + sn * 16 + l16;
#pragma unroll
      for (int r = 0; r < 4; ++r)
        out[(size_t)(row0 + r) * OUT_DIM + col] = acc[sm][sn][r];
    }
}

extern "C" void kernel_launch(void* const* d_in, const int* in_sizes, int n_in,
                              void* d_out, int out_size, void* d_ws, size_t ws_size,
                              hipStream_t stream) {
  const float* x     = (const float*)d_in[0];
  const float* grid  = (const float*)d_in[1];
  const float* coeff = (const float*)d_in[2];
  const float* sb    = (const float*)d_in[3];
  const float* ss    = (const float*)d_in[4];
  float* out = (float*)d_out;

  u16* Wt = (u16*)d_ws;   // 25.2 MB; rest of ws unused now

  pack_wt_kernel<<<(OUT_DIM * IN_DIM) / 256, 256, 0, stream>>>(coeff, sb, ss, Wt);
  gemm_fused_kernel<<<(TOKENS / 128) * 8, 256, 0, stream>>>(x, grid, Wt, out);
}

// Round 4
// 430.937 us; speedup vs baseline: 1.6472x; 1.3210x over previous
//
#include <hip/hip_runtime.h>
#include <hip/hip_bf16.h>
#include <stdint.h>

typedef __attribute__((ext_vector_type(8))) short short8;
typedef __attribute__((ext_vector_type(4))) float floatx4;
typedef unsigned short u16;

#define IN_DIM  1024
#define OUT_DIM 1024
#define NG      11            // spline bases per channel
#define GK      12            // + silu slot
#define KDIM    (IN_DIM * GK) // 12288
#define TOKENS  8192
#define BK      64            // K-tile: 2 mfma k-steps

__device__ __forceinline__ u16 f2bf(float f) {
  uint32_t u = __float_as_uint(f);
  uint32_t r = (u + 0x7fffu + ((u >> 16) & 1u)) >> 16;  // RNE
  return (u16)r;
}

// ---------------- pack Wt: bf16 [OUT_DIM][KDIM]; group i: coeff[o][i][0..10]*ss, scale_base[o][i]
__global__ __launch_bounds__(256) void pack_wt_kernel(
    const float* __restrict__ coeff, const float* __restrict__ sb,
    const float* __restrict__ ss_p, u16* __restrict__ Wt)
{
  __shared__ __align__(16) u16 st[256 * GK];
  int tid = threadIdx.x;
  int idx = blockIdx.x * 256 + tid;
  int o = idx >> 10, i = idx & 1023;
  float ss = ss_p[0];
  const float* cp = coeff + (size_t)o * (IN_DIM * NG) + (size_t)i * NG;
  u16* s = st + tid * GK;
#pragma unroll
  for (int g = 0; g < NG; ++g) s[g] = f2bf(cp[g] * ss);
  s[NG] = f2bf(sb[(size_t)o * IN_DIM + i]);
  __syncthreads();
  const uint4* src = (const uint4*)st;
  uint4* dst = (uint4*)(Wt + (size_t)blockIdx.x * (256 * GK));
  dst[tid] = src[tid];
  if (tid < 128) dst[256 + tid] = src[256 + tid];
}

// ---------------- expand: closed-form cubic B-spline (uniform grid), register funnel placement,
// LDS-staged coalesced stores. Math identical to R3's verified expand_store (absmax 0.125).
__global__ __launch_bounds__(256) void expand_kernel(
    const float* __restrict__ X, const float* __restrict__ grid,
    u16* __restrict__ A, int m0)
{
  __shared__ __align__(16) u16 st[256 * GK];   // 6144 B
  int tid = threadIdx.x;
  int idx = blockIdx.x * 256 + tid;            // (rows*1024) threads, channel fastest
  float x = X[(size_t)m0 * IN_DIM + idx];

  const float g0    = grid[0];
  const float inv_h = 1.0f / (grid[1] - grid[0]);   // uniform grid (tiled arange row)

  float t  = (x - g0) * inv_h;
  float fc = floorf(t);
  int   c  = (int)fc;
  float u  = t - fc;
  float u2 = u * u;
  float w1 = 1.0f - u;
  float b0 = (w1 * w1 * w1) * (1.0f / 6.0f);                        // slot c-3
  float b1 = (0.5f * u - 1.0f) * u2 + (2.0f / 3.0f);                // slot c-2
  float b2 = ((-0.5f * u + 0.5f) * u + 0.5f) * u + (1.0f / 6.0f);   // slot c-1
  float b3 = (u2 * u) * (1.0f / 6.0f);                              // slot c
  float sil = x / (1.0f + __expf(-x));

  // payload: 4 pieces as bf16, LSB-first
  uint64_t P = (uint64_t)f2bf(b0) | ((uint64_t)f2bf(b1) << 16)
             | ((uint64_t)f2bf(b2) << 32) | ((uint64_t)f2bf(b3) << 48);
  int  k  = c - 3;                       // slot index of b0
  bool cv = (c >= 0) && (c <= 13);       // else all bases zero (x outside knot window)
  int  kneg = (k < 0) ? -k : 0;          // low-side clip (0..3)
  uint64_t Pc = cv ? (P >> (16 * kneg)) : 0ull;
  uint32_t sh = (uint32_t)(16 * ((k < 0) ? 0 : k));   // 0..160, multiple of 16

  // place Pc into 192-bit V2:V1:V0 at bit offset sh (guarded shifts; &63 keeps C defined)
  uint64_t V0 = (sh < 64)  ? (Pc << (sh & 63)) : 0ull;
  uint64_t V1 = (sh == 0)  ? 0ull :
                (sh < 64)  ? (Pc >> ((64 - sh) & 63)) :
                (sh < 128) ? (Pc << ((sh - 64) & 63)) : 0ull;
  uint64_t V2 = (sh <= 64) ? 0ull :
                (sh < 128) ? (Pc >> ((128 - sh) & 63)) :
                             (Pc << ((sh - 128) & 63));
  // slot 11 = silu (also clears any k=10 spill of b1 into slot 11; slots 12/13 fell off the top)
  V2 = (V2 & 0x0000FFFFFFFFFFFFull) | ((uint64_t)f2bf(sil) << 48);

  uint64_t* sp = (uint64_t*)(st + tid * GK);   // 24B per thread, 8B aligned; stride 6 dwords -> 2-way (free)
  sp[0] = V0; sp[1] = V1; sp[2] = V2;
  __syncthreads();

  const uint4* src = (const uint4*)st;         // 384 uint4
  uint4* dst = (uint4*)(A + (size_t)blockIdx.x * (256 * GK));
  dst[tid] = src[tid];
  if (tid < 128) dst[256 + tid] = src[256 + tid];
}

// ---------------- GEMM: out = A[rows][KDIM] * Wt[1024][KDIM]^T  (R2 structure, fixed XCD swizzle)
__device__ __forceinline__ void async16(const u16* g, u16* l) {
  __builtin_amdgcn_global_load_lds(
      (const __attribute__((address_space(1))) uint32_t*)g,
      (__attribute__((address_space(3))) uint32_t*)l,
      16, 0, 0);
}

__global__ __launch_bounds__(256) void gemm_kernel(
    const u16* __restrict__ A, const u16* __restrict__ Wt,
    float* __restrict__ out, int m0, int mtiles)
{
  // XOR-swizzled LDS (R2: zero bank conflicts). Row stride BK=64 u16 = 128 B.
  __shared__ __align__(16) u16 As[128 * BK];   // 16 KB
  __shared__ __align__(16) u16 Bs[128 * BK];   // 16 KB

  const int tid  = threadIdx.x;
  const int lane = tid & 63;
  const int wave = tid >> 6;
  // A-locality swizzle: blocks sharing an A-strip (same bm) have blockIdx ≡ bm (mod mtiles),
  // hence ≡ bm (mod 8) -> same XCD -> each A K-slice is fetched from HBM once, then L2-hit.
  // Wt (25 MB total) re-reads across XCDs are absorbed by L3.
  const int bm = blockIdx.x % mtiles;
  const int bn = blockIdx.x / mtiles;
  const int wm = (wave >> 1) * 64;
  const int wn = (wave & 1) * 64;

  floatx4 acc[4][4];
#pragma unroll
  for (int a = 0; a < 4; ++a)
#pragma unroll
    for (int b = 0; b < 4; ++b) acc[a][b] = (floatx4){0.f, 0.f, 0.f, 0.f};

  // Staging: each async16 covers 8 rows x 128B. Lane l -> LDS slot (row=l>>3, chunk=l&7);
  // lane fetches global chunk gamma=(l&7)^(l>>3) so LDS holds chunk c of row r at slot c^(r&7).
  const int srow  = lane >> 3;
  const int gamma = (lane & 7) ^ srow;
  const u16* Ag = A  + (size_t)(bm * 128 + wave * 32 + srow) * KDIM + gamma * 8;
  const u16* Bg = Wt + (size_t)(bn * 128 + wave * 32 + srow) * KDIM + gamma * 8;
  u16* Al = As + (wave * 32) * BK;
  u16* Bl = Bs + (wave * 32) * BK;

  const int quad = lane >> 4;
  const int l16  = lane & 15;
  const int sw   = l16 & 7;          // read-side swizzle key (row&7 == l16&7)

  for (int k0 = 0; k0 < KDIM; k0 += BK) {
#pragma unroll
    for (int op = 0; op < 4; ++op) {
      async16(Ag + k0 + (size_t)(op * 8) * KDIM, Al + op * 8 * BK);
      async16(Bg + k0 + (size_t)(op * 8) * KDIM, Bl + op * 8 * BK);
    }
    __syncthreads();

    short8 af[4][2], bf[4][2];
#pragma unroll
    for (int s = 0; s < 4; ++s)
#pragma unroll
      for (int t = 0; t < 2; ++t) {
        int cc = (t * 4 + quad) ^ sw;
        af[s][t] = *(const short8*)&As[(wm + s * 16 + l16) * BK + cc * 8];
        bf[s][t] = *(const short8*)&Bs[(wn + s * 16 + l16) * BK + cc * 8];
      }

#pragma unroll
    for (int sm = 0; sm < 4; ++sm)
#pragma unroll
      for (int sn = 0; sn < 4; ++sn)
#pragma unroll
        for (int t = 0; t < 2; ++t)
          acc[sm][sn] = __builtin_amdgcn_mfma_f32_16x16x32_bf16(af[sm][t], bf[sn][t], acc[sm][sn], 0, 0, 0);

    __syncthreads();
  }

  // epilogue: C/D map col=lane&15, row=(lane>>4)*4+reg
#pragma unroll
  for (int sm = 0; sm < 4; ++sm)
#pragma unroll
    for (int sn = 0; sn < 4; ++sn) {
      int row0 = m0 + bm * 128 + wm + sm * 16 + quad * 4;
      int col  = bn * 128 + wn + sn * 16 + l16;
#pragma unroll
      for (int r = 0; r < 4; ++r)
        out[(size_t)(row0 + r) * OUT_DIM + col] = acc[sm][sn][r];
    }
}

extern "C" void kernel_launch(void* const* d_in, const int* in_sizes, int n_in,
                              void* d_out, int out_size, void* d_ws, size_t ws_size,
                              hipStream_t stream) {
  const float* x     = (const float*)d_in[0];
  const float* grid  = (const float*)d_in[1];
  const float* coeff = (const float*)d_in[2];
  const float* sb    = (const float*)d_in[3];
  const float* ss    = (const float*)d_in[4];
  float* out = (float*)d_out;

  u16* Wt = (u16*)d_ws;
  const size_t wt_bytes = (size_t)OUT_DIM * KDIM * 2;   // 25.2 MB
  u16* Abuf = (u16*)((char*)d_ws + wt_bytes);

  size_t avail   = ws_size > wt_bytes ? ws_size - wt_bytes : 0;
  size_t maxrows = avail / ((size_t)KDIM * 2);
  int chunk = (int)(maxrows & ~(size_t)127);
  if (chunk > TOKENS) chunk = TOKENS;
  if (chunk < 128)    chunk = 128;

  pack_wt_kernel<<<(OUT_DIM * IN_DIM) / 256, 256, 0, stream>>>(coeff, sb, ss, Wt);

  for (int m0 = 0; m0 < TOKENS; m0 += chunk) {
    int rows = TOKENS - m0 < chunk ? TOKENS - m0 : chunk;   // multiple of 128
    expand_kernel<<<(rows * IN_DIM) / 256, 256, 0, stream>>>(x, grid, Abuf, m0);
    gemm_kernel<<<(rows / 128) * 8, 256, 0, stream>>>(Abuf, Wt, out, m0, rows / 128);
  }
}